// Round 5
// baseline (228.059 us; speedup 1.0000x reference)
//
#include <hip/hip_runtime.h>
#include <math.h>

// Word2Vec negative-sampling loss — round 4 (retry; GPU timeout).
// One 64-lane wave owns one batch element. 8-lane groups gather one 512B row
// as 4 x (full 128B line per load instruction): lane sub reads bytes
// [c*128 + sub*16, +16) for c=0..3 — every L2 request is a full aligned line.
// 8 rows in flight per wave per iteration, 14 iterations (110 rows, 98% eff).
// No LDS, no barriers; reductions entirely via shfl_xor.

#define O_WIN 10
#define K_NEG 10
#define DIM   128
#define ROWS  (O_WIN * (K_NEG + 1))   // 110

__global__ __launch_bounds__(256) void w2v_neg_loss_kernel(
    const float* __restrict__ center,    // [VOCAB, 128]
    const float* __restrict__ outside,   // [VOCAB, 128]
    const int*   __restrict__ cidx,      // [B]
    const int*   __restrict__ owi,       // [B, O]
    const int*   __restrict__ negs,      // [B, O, K]
    float*       __restrict__ out)       // [B]
{
    const int tid  = threadIdx.x;
    const int wave = tid >> 6;
    const int lane = tid & 63;
    const int sub  = lane & 7;    // lane within 8-lane row group
    const int grp  = lane >> 3;   // 8 row groups per wave

    const int b = blockIdx.x * 4 + wave;   // one wave per batch element

    // Z fragment: lane sub owns floats {c*32 + sub*4 .. +4} for c=0..3
    // (matches the 128B-line W chunks below). Wave-uniform row -> L1 broadcast.
    const int    c    = cidx[b];
    const float* zrow = center + (size_t)c * DIM;
    float4 zf[4];
    #pragma unroll
    for (int q = 0; q < 4; ++q)
        zf[q] = *reinterpret_cast<const float4*>(zrow + q * 32 + sub * 4);

    const int* ow_b  = owi  + (size_t)b * O_WIN;
    const int* neg_b = negs + (size_t)b * (O_WIN * K_NEG);

    float acc = 0.f;

    #pragma unroll 2
    for (int it = 0; it < 14; ++it) {
        const int r   = grp + (it << 3);       // this group's row this iter
        const bool inr = (r < ROWS);
        const int rr  = inr ? r : 0;
        const int o   = rr / 11;
        const int j   = rr - o * 11;           // 0 = positive, 1..10 = negative
        // all 8 lanes of the group load the same scalars -> L1 broadcast
        const int ow  = ow_b[o];
        const int nx  = neg_b[o * K_NEG + (j == 0 ? 0 : j - 1)];
        const int idx = (j == 0) ? ow : nx;
        const bool valid = inr && (ow != 0) && (idx != 0);

        const float* wrow = outside + (size_t)idx * DIM;
        float p = 0.f;
        #pragma unroll
        for (int q = 0; q < 4; ++q) {
            const float4 w = *reinterpret_cast<const float4*>(
                wrow + q * 32 + sub * 4);
            p += w.x * zf[q].x + w.y * zf[q].y + w.z * zf[q].z + w.w * zf[q].w;
        }
        // 3-level butterfly within the 8-lane group — all 8 get the row sum
        p += __shfl_xor(p, 1);
        p += __shfl_xor(p, 2);
        p += __shfl_xor(p, 4);

        const float score = (j == 0) ? p : -p;
        // exact stable log-sigmoid: min(x,0) - log1p(exp(-|x|))
        const float ls = fminf(score, 0.f) - log1pf(expf(-fabsf(score)));
        acc += valid ? ls : 0.f;
    }

    // cross-group reduce: each lane holds its group's sum (identical within
    // group); masks {8,16,32} add each of the 8 groups exactly once.
    acc += __shfl_xor(acc, 8);
    acc += __shfl_xor(acc, 16);
    acc += __shfl_xor(acc, 32);

    if (lane == 0) out[b] = -acc;
}

extern "C" void kernel_launch(void* const* d_in, const int* in_sizes, int n_in,
                              void* d_out, int out_size, void* d_ws, size_t ws_size,
                              hipStream_t stream) {
    const float* center  = (const float*)d_in[0];
    const float* outside = (const float*)d_in[1];
    const int*   cw      = (const int*)d_in[2];
    const int*   ow      = (const int*)d_in[3];
    const int*   ng      = (const int*)d_in[4];
    float*       out     = (float*)d_out;

    const int B = in_sizes[2];   // 16384, divisible by 4
    w2v_neg_loss_kernel<<<B / 4, 256, 0, stream>>>(center, outside, cw, ow, ng, out);
}

// Round 6
// 178.058 us; speedup vs baseline: 1.2808x; 1.2808x over previous
//
#include <hip/hip_runtime.h>
#include <math.h>

// Word2Vec negative-sampling loss — round 6: bf16 gather table.
// Rounds 3+5 both pinned at ~120us with 434MB L2-miss traffic @ ~3.5TB/s
// regardless of VALU load -> L2<->L3 gather fabric is the limiter.
// Lever: halve gather BYTES. Pre-pass converts outside_vectors (51.2MB f32)
// to bf16 (25.6MB) in d_ws; main kernel gathers 256B rows (2 x 128B lines),
// unpacks bf16->f32 in-register, f32 Z + f32 accumulate, fast logsig.

#define O_WIN 10
#define K_NEG 10
#define DIM   128
#define ROWS  (O_WIN * (K_NEG + 1))   // 110

// ---- pre-pass: f32 -> bf16 (RNE), 8 elements/thread --------------------
__device__ __forceinline__ unsigned pack2_bf16(float a, float b) {
    unsigned ua = __float_as_uint(a);
    unsigned ub = __float_as_uint(b);
    ua = (ua + 0x7FFFu + ((ua >> 16) & 1u)) >> 16;   // RNE (no NaN in data)
    ub = (ub + 0x7FFFu + ((ub >> 16) & 1u)) >> 16;
    return ua | (ub << 16);
}

__global__ __launch_bounds__(256) void convert_bf16_kernel(
    const float* __restrict__ src, unsigned* __restrict__ dst, int n8)
{
    const int i = blockIdx.x * 256 + threadIdx.x;   // one uint4 = 8 floats
    if (i >= n8) return;
    const float4 a = reinterpret_cast<const float4*>(src)[2 * i];
    const float4 b = reinterpret_cast<const float4*>(src)[2 * i + 1];
    uint4 o;
    o.x = pack2_bf16(a.x, a.y);
    o.y = pack2_bf16(a.z, a.w);
    o.z = pack2_bf16(b.x, b.y);
    o.w = pack2_bf16(b.z, b.w);
    reinterpret_cast<uint4*>(dst)[i] = o;
}

// ---- main: bf16 gathers ------------------------------------------------
// One wave per batch element. 8-lane groups, row = 256B = 2 x (128B line):
// chunk q (q=0,1): lane sub reads uint4 at byte q*128 + sub*16, covering
// row elements [q*64 + sub*8, +8). Z fragment mirrors that mapping in f32.
__global__ __launch_bounds__(256) void w2v_neg_loss_bf16_kernel(
    const float*    __restrict__ center,     // [VOCAB, 128] f32
    const unsigned* __restrict__ outsideb,   // [VOCAB, 128] bf16 packed as u32 pairs
    const int*      __restrict__ cidx,
    const int*      __restrict__ owi,
    const int*      __restrict__ negs,
    float*          __restrict__ out)
{
    const int tid  = threadIdx.x;
    const int wave = tid >> 6;
    const int lane = tid & 63;
    const int sub  = lane & 7;
    const int grp  = lane >> 3;

    const int b = blockIdx.x * 4 + wave;

    const int    c    = cidx[b];
    const float* zrow = center + (size_t)c * DIM;
    float zf[2][8];
    #pragma unroll
    for (int q = 0; q < 2; ++q) {
        const float4 lo = *reinterpret_cast<const float4*>(zrow + q * 64 + sub * 8);
        const float4 hi = *reinterpret_cast<const float4*>(zrow + q * 64 + sub * 8 + 4);
        zf[q][0] = lo.x; zf[q][1] = lo.y; zf[q][2] = lo.z; zf[q][3] = lo.w;
        zf[q][4] = hi.x; zf[q][5] = hi.y; zf[q][6] = hi.z; zf[q][7] = hi.w;
    }

    const int* ow_b  = owi  + (size_t)b * O_WIN;
    const int* neg_b = negs + (size_t)b * (O_WIN * K_NEG);

    float acc = 0.f;

    #pragma unroll 2
    for (int it = 0; it < 14; ++it) {
        const int  r   = grp + (it << 3);
        const bool inr = (r < ROWS);
        const int  rr  = inr ? r : 0;
        const int  o   = rr / 11;
        const int  j   = rr - o * 11;          // 0 = positive, 1..10 = negative
        const int  ow  = ow_b[o];
        const int  nx  = neg_b[o * K_NEG + (j == 0 ? 0 : j - 1)];
        const int  idx = (j == 0) ? ow : nx;
        const bool valid = inr && (ow != 0) && (idx != 0);

        // row base: 128 bf16 = 32 u32 = 8 uint4 per row
        const uint4* wrow = reinterpret_cast<const uint4*>(
            outsideb + (size_t)idx * (DIM / 2));

        float p = 0.f;
        #pragma unroll
        for (int q = 0; q < 2; ++q) {
            const uint4 w = wrow[q * 8 + sub];
            const unsigned u[4] = { w.x, w.y, w.z, w.w };
            #pragma unroll
            for (int k = 0; k < 4; ++k) {
                const float flo = __uint_as_float(u[k] << 16);
                const float fhi = __uint_as_float(u[k] & 0xFFFF0000u);
                p += flo * zf[q][2 * k] + fhi * zf[q][2 * k + 1];
            }
        }
        p += __shfl_xor(p, 1);
        p += __shfl_xor(p, 2);
        p += __shfl_xor(p, 4);

        const float score = (j == 0) ? p : -p;
        // fast stable log-sigmoid (v_exp/v_log single-instr)
        const float ls = fminf(score, 0.f) - __logf(1.f + __expf(-fabsf(score)));
        acc += valid ? ls : 0.f;
    }

    acc += __shfl_xor(acc, 8);
    acc += __shfl_xor(acc, 16);
    acc += __shfl_xor(acc, 32);

    if (lane == 0) out[b] = -acc;
}

// ---- f32 fallback (round-5 kernel) if ws too small ---------------------
__global__ __launch_bounds__(256) void w2v_neg_loss_f32_kernel(
    const float* __restrict__ center,
    const float* __restrict__ outside,
    const int*   __restrict__ cidx,
    const int*   __restrict__ owi,
    const int*   __restrict__ negs,
    float*       __restrict__ out)
{
    const int tid  = threadIdx.x;
    const int wave = tid >> 6;
    const int lane = tid & 63;
    const int sub  = lane & 7;
    const int grp  = lane >> 3;
    const int b = blockIdx.x * 4 + wave;

    const int    c    = cidx[b];
    const float* zrow = center + (size_t)c * DIM;
    float4 zf[4];
    #pragma unroll
    for (int q = 0; q < 4; ++q)
        zf[q] = *reinterpret_cast<const float4*>(zrow + q * 32 + sub * 4);

    const int* ow_b  = owi  + (size_t)b * O_WIN;
    const int* neg_b = negs + (size_t)b * (O_WIN * K_NEG);
    float acc = 0.f;

    #pragma unroll 2
    for (int it = 0; it < 14; ++it) {
        const int  r   = grp + (it << 3);
        const bool inr = (r < ROWS);
        const int  rr  = inr ? r : 0;
        const int  o   = rr / 11;
        const int  j   = rr - o * 11;
        const int  ow  = ow_b[o];
        const int  nx  = neg_b[o * K_NEG + (j == 0 ? 0 : j - 1)];
        const int  idx = (j == 0) ? ow : nx;
        const bool valid = inr && (ow != 0) && (idx != 0);

        const float* wrow = outside + (size_t)idx * DIM;
        float p = 0.f;
        #pragma unroll
        for (int q = 0; q < 4; ++q) {
            const float4 w = *reinterpret_cast<const float4*>(wrow + q * 32 + sub * 4);
            p += w.x * zf[q].x + w.y * zf[q].y + w.z * zf[q].z + w.w * zf[q].w;
        }
        p += __shfl_xor(p, 1);
        p += __shfl_xor(p, 2);
        p += __shfl_xor(p, 4);

        const float score = (j == 0) ? p : -p;
        const float ls = fminf(score, 0.f) - log1pf(expf(-fabsf(score)));
        acc += valid ? ls : 0.f;
    }
    acc += __shfl_xor(acc, 8);
    acc += __shfl_xor(acc, 16);
    acc += __shfl_xor(acc, 32);
    if (lane == 0) out[b] = -acc;
}

extern "C" void kernel_launch(void* const* d_in, const int* in_sizes, int n_in,
                              void* d_out, int out_size, void* d_ws, size_t ws_size,
                              hipStream_t stream) {
    const float* center  = (const float*)d_in[0];
    const float* outside = (const float*)d_in[1];
    const int*   cw      = (const int*)d_in[2];
    const int*   ow      = (const int*)d_in[3];
    const int*   ng      = (const int*)d_in[4];
    float*       out     = (float*)d_out;

    const int B    = in_sizes[2];        // 16384, divisible by 4
    const int nOut = in_sizes[1];        // VOCAB*DIM = 12.8M

    if (ws_size >= (size_t)nOut * sizeof(unsigned short)) {
        unsigned* outsideb = (unsigned*)d_ws;
        const int n8 = nOut / 8;         // uint4 units
        convert_bf16_kernel<<<(n8 + 255) / 256, 256, 0, stream>>>(
            outside, outsideb, n8);
        w2v_neg_loss_bf16_kernel<<<B / 4, 256, 0, stream>>>(
            center, outsideb, cw, ow, ng, out);
    } else {
        w2v_neg_loss_f32_kernel<<<B / 4, 256, 0, stream>>>(
            center, outside, cw, ow, ng, out);
    }
}

// Round 7
// 148.754 us; speedup vs baseline: 1.5331x; 1.1970x over previous
//
#include <hip/hip_runtime.h>
#include <math.h>

// Word2Vec negative-sampling loss — round 7: int8 gather table (per-row scale).
// r3/r5/r6 establish the kernel is BYTE-bound on the L2-miss gather path at a
// ~3.4 TB/s fabric plateau (bytes halved -> time halved, rate constant).
// Lever: halve bytes again. outside row -> 128 int8 (one 128B L2 line) +
// per-row f32 scale (400KB, L2-resident). Z quantized in-kernel per wave
// (per-row scale). Dot via sdot4 (v_dot4_i32_i8) when available.
// Log-sigmoid de-dup: claim-select scores during the unrolled loop (static
// indices), masked scores = +1e30 (exact logsig -> 0), ~2 exact logsigs/lane.

#define O_WIN 10
#define K_NEG 10
#define DIM   128
#define ROWS  (O_WIN * (K_NEG + 1))   // 110
#define VROW_U32 (DIM / 4)            // 32 u32 per int8 row

#if defined(__has_builtin)
#  if __has_builtin(__builtin_amdgcn_sdot4)
#    define HAVE_SDOT4 1
#  endif
#endif

__device__ __forceinline__ int dot4acc(unsigned a, unsigned b, int c) {
#ifdef HAVE_SDOT4
    return __builtin_amdgcn_sdot4((int)a, (int)b, c, false);
#else
    #pragma unroll
    for (int k = 0; k < 4; ++k) {
        const int xa = (int)(a << (24 - 8 * k)) >> 24;   // sext byte k
        const int xb = (int)(b << (24 - 8 * k)) >> 24;
        c += xa * xb;
    }
    return c;
#endif
}

__device__ __forceinline__ unsigned pack4_q(float4 f, float inv) {
    const int a = (int)rintf(f.x * inv) & 0xFF;
    const int b = (int)rintf(f.y * inv) & 0xFF;
    const int c = (int)rintf(f.z * inv) & 0xFF;
    const int d = (int)rintf(f.w * inv) & 0xFF;
    return (unsigned)(a | (b << 8) | (c << 16) | (d << 24));
}

// exact stable log-sigmoid; logsig(+1e30) == 0 exactly (masked sentinel)
__device__ __forceinline__ float logsig(float x) {
    return fminf(x, 0.f) - log1pf(__expf(-fabsf(x)));
}

// ---- pre-pass: per-row int8 quantization of the outside table ----------
// one 8-lane group per row; lane sub covers elements [sub*16, sub*16+16)
__global__ __launch_bounds__(256) void quant_rows_kernel(
    const float* __restrict__ src,     // [V,128] f32
    unsigned*    __restrict__ wq,      // [V,32]  int8 packed
    float*       __restrict__ wscale,  // [V]
    int vocab)
{
    const int tid = threadIdx.x;
    const int sub = tid & 7;
    const int row = blockIdx.x * 32 + (tid >> 3);
    if (row >= vocab) return;

    const float* r = src + (size_t)row * DIM + sub * 16;
    float4 f[4];
    float m = 0.f;
    #pragma unroll
    for (int u = 0; u < 4; ++u) {
        f[u] = *reinterpret_cast<const float4*>(r + u * 4);
        m = fmaxf(m, fmaxf(fmaxf(fabsf(f[u].x), fabsf(f[u].y)),
                           fmaxf(fabsf(f[u].z), fabsf(f[u].w))));
    }
    m = fmaxf(m, __shfl_xor(m, 1));
    m = fmaxf(m, __shfl_xor(m, 2));
    m = fmaxf(m, __shfl_xor(m, 4));
    const float inv = (m > 0.f) ? 127.f / m : 0.f;

    uint4 o;
    o.x = pack4_q(f[0], inv);
    o.y = pack4_q(f[1], inv);
    o.z = pack4_q(f[2], inv);
    o.w = pack4_q(f[3], inv);
    *reinterpret_cast<uint4*>(wq + (size_t)row * VROW_U32 + sub * 4) = o;
    if (sub == 0) wscale[row] = m * (1.f / 127.f);
}

// ---- main: int8 gathers, one wave per batch element --------------------
__global__ __launch_bounds__(256) void w2v_i8_kernel(
    const float*    __restrict__ center,   // [V,128] f32
    const unsigned* __restrict__ wq,       // [V,32]  int8 packed
    const float*    __restrict__ wscale,   // [V]
    const int*      __restrict__ cidx,
    const int*      __restrict__ owi,
    const int*      __restrict__ negs,
    float*          __restrict__ out)
{
    const int tid  = threadIdx.x;
    const int wave = tid >> 6;
    const int lane = tid & 63;
    const int sub  = lane & 7;    // lane within 8-lane row group
    const int grp  = lane >> 3;   // 8 row groups per wave

    const int b = blockIdx.x * 4 + wave;

    // Z: load f32 slice, per-row-scale int8 quantize in-register.
    // lane sub covers elements [sub*16, +16), matching W byte layout.
    const float* zrow = center + (size_t)cidx[b] * DIM + sub * 16;
    float4 zf[4];
    float zm = 0.f;
    #pragma unroll
    for (int u = 0; u < 4; ++u) {
        zf[u] = *reinterpret_cast<const float4*>(zrow + u * 4);
        zm = fmaxf(zm, fmaxf(fmaxf(fabsf(zf[u].x), fabsf(zf[u].y)),
                             fmaxf(fabsf(zf[u].z), fabsf(zf[u].w))));
    }
    zm = fmaxf(zm, __shfl_xor(zm, 1));
    zm = fmaxf(zm, __shfl_xor(zm, 2));
    zm = fmaxf(zm, __shfl_xor(zm, 4));   // full-row max (group-replicated)
    const float zinv = (zm > 0.f) ? 127.f / zm : 0.f;
    const float zsc  = zm * (1.f / 127.f);
    unsigned zq[4];
    #pragma unroll
    for (int u = 0; u < 4; ++u) zq[u] = pack4_q(zf[u], zinv);

    const int* ow_b  = owi  + (size_t)b * O_WIN;
    const int* neg_b = negs + (size_t)b * (O_WIN * K_NEG);

    // claim-selected scores: lane sub owns iterations it==sub and it==sub+8
    float sel0 = 1e30f, sel1 = 1e30f;

    #pragma unroll
    for (int it = 0; it < 14; ++it) {
        const int  r   = grp + (it << 3);
        const bool inr = (r < ROWS);
        const int  rr  = inr ? r : 0;
        const int  o   = rr / 11;
        const int  j   = rr - o * 11;          // 0 = positive, 1..10 = negative
        const int  ow  = ow_b[o];
        const int  nx  = neg_b[o * K_NEG + (j == 0 ? 0 : j - 1)];
        const int  idx = (j == 0) ? ow : nx;
        const bool valid = inr && (ow != 0) && (idx != 0);

        // one full 128B line per row: lane sub reads uint4 at byte sub*16
        const uint4 w = *reinterpret_cast<const uint4*>(
            wq + (size_t)idx * VROW_U32 + sub * 4);
        const float wsc = wscale[idx];

        int d = 0;
        d = dot4acc(w.x, zq[0], d);
        d = dot4acc(w.y, zq[1], d);
        d = dot4acc(w.z, zq[2], d);
        d = dot4acc(w.w, zq[3], d);
        // int butterfly within the 8-lane group
        d += __shfl_xor(d, 1);
        d += __shfl_xor(d, 2);
        d += __shfl_xor(d, 4);

        const float p     = (float)d * (wsc * zsc);
        float       score = (j == 0) ? p : -p;
        score = valid ? score : 1e30f;         // masked -> logsig 0

        const bool claim = ((it & 7) == sub);  // static it&7 vs runtime sub
        if (it < 8) sel0 = claim ? score : sel0;   // it<8 is compile-time
        else        sel1 = claim ? score : sel1;
    }

    // each lane: ~2 exact logsigs (subs 6,7 keep sel1=1e30 -> 0)
    float acc = logsig(sel0) + logsig(sel1);

    // full 64-lane butterfly: every claimed score counted exactly once
    acc += __shfl_xor(acc, 1);
    acc += __shfl_xor(acc, 2);
    acc += __shfl_xor(acc, 4);
    acc += __shfl_xor(acc, 8);
    acc += __shfl_xor(acc, 16);
    acc += __shfl_xor(acc, 32);

    if (lane == 0) out[b] = -acc;
}

// ---- f32 fallback (round-5 kernel) if ws too small ---------------------
__global__ __launch_bounds__(256) void w2v_neg_loss_f32_kernel(
    const float* __restrict__ center,
    const float* __restrict__ outside,
    const int*   __restrict__ cidx,
    const int*   __restrict__ owi,
    const int*   __restrict__ negs,
    float*       __restrict__ out)
{
    const int tid  = threadIdx.x;
    const int wave = tid >> 6;
    const int lane = tid & 63;
    const int sub  = lane & 7;
    const int grp  = lane >> 3;
    const int b = blockIdx.x * 4 + wave;

    const int    c    = cidx[b];
    const float* zrow = center + (size_t)c * DIM;
    float4 zf[4];
    #pragma unroll
    for (int q = 0; q < 4; ++q)
        zf[q] = *reinterpret_cast<const float4*>(zrow + q * 32 + sub * 4);

    const int* ow_b  = owi  + (size_t)b * O_WIN;
    const int* neg_b = negs + (size_t)b * (O_WIN * K_NEG);
    float acc = 0.f;

    #pragma unroll 2
    for (int it = 0; it < 14; ++it) {
        const int  r   = grp + (it << 3);
        const bool inr = (r < ROWS);
        const int  rr  = inr ? r : 0;
        const int  o   = rr / 11;
        const int  j   = rr - o * 11;
        const int  ow  = ow_b[o];
        const int  nx  = neg_b[o * K_NEG + (j == 0 ? 0 : j - 1)];
        const int  idx = (j == 0) ? ow : nx;
        const bool valid = inr && (ow != 0) && (idx != 0);

        const float* wrow = outside + (size_t)idx * DIM;
        float p = 0.f;
        #pragma unroll
        for (int q = 0; q < 4; ++q) {
            const float4 w = *reinterpret_cast<const float4*>(wrow + q * 32 + sub * 4);
            p += w.x * zf[q].x + w.y * zf[q].y + w.z * zf[q].z + w.w * zf[q].w;
        }
        p += __shfl_xor(p, 1);
        p += __shfl_xor(p, 2);
        p += __shfl_xor(p, 4);

        const float score = (j == 0) ? p : -p;
        const float ls = fminf(score, 0.f) - log1pf(expf(-fabsf(score)));
        acc += valid ? ls : 0.f;
    }
    acc += __shfl_xor(acc, 8);
    acc += __shfl_xor(acc, 16);
    acc += __shfl_xor(acc, 32);
    if (lane == 0) out[b] = -acc;
}

extern "C" void kernel_launch(void* const* d_in, const int* in_sizes, int n_in,
                              void* d_out, int out_size, void* d_ws, size_t ws_size,
                              hipStream_t stream) {
    const float* center  = (const float*)d_in[0];
    const float* outside = (const float*)d_in[1];
    const int*   cw      = (const int*)d_in[2];
    const int*   ow      = (const int*)d_in[3];
    const int*   ng      = (const int*)d_in[4];
    float*       out     = (float*)d_out;

    const int B     = in_sizes[2];          // 16384, divisible by 4
    const int nOut  = in_sizes[1];          // VOCAB*DIM
    const int vocab = nOut / DIM;           // 100000

    const size_t wq_bytes = (size_t)vocab * DIM;            // int8 table
    const size_t need     = wq_bytes + (size_t)vocab * 4;   // + scales

    if (ws_size >= need) {
        unsigned* wq     = (unsigned*)d_ws;
        float*    wscale = (float*)((char*)d_ws + wq_bytes);
        quant_rows_kernel<<<(vocab + 31) / 32, 256, 0, stream>>>(
            outside, wq, wscale, vocab);
        w2v_i8_kernel<<<B / 4, 256, 0, stream>>>(
            center, wq, wscale, cw, ow, ng, out);
    } else {
        w2v_neg_loss_f32_kernel<<<B / 4, 256, 0, stream>>>(
            center, outside, cw, ow, ng, out);
    }
}